// Round 8
// baseline (282.444 us; speedup 1.0000x reference)
//
#include <hip/hip_runtime.h>
#include <float.h>

// VectorQuantizer: B=16,T=4096,D=256,K=1024 fp32.
// Round 10: TOKENS-IN-LDS. Register accounting across r3-r7 showed every
//   variant ran at ~2 waves/SIMD because resident bfrag (64 tok x K256 f16)
//   costs 128 regs in ANY shape. Fix: the 64-token tile is 32KB f16 -> stage
//   it ONCE in LDS (fragment-ordered, read-only after init, ZERO in-loop
//   barriers), read bf via contiguous conflict-free ds_read_b128; af streams
//   from L2-resident tiled cht 2 slices deep. Regs ~160 -> 3 waves/SIMD
//   (launch_bounds(256,3)); cover = 2 slices x 80cy x 3 waves ~ 480cy >> L2.
//   Waves split codes 4-way (64/chunk, 4 chunks of 256). Packed-index top-2
//   (r7-verified) j = nc*16+ci*4+r < 64; 4-way wave merge (rescue-verified
//   pattern). prep = r4 verified (tiled cht); rescue = r5 verified.
//   Score space: score = x.c - 0.5*c2  (argmin d2 == argmax score).

typedef _Float16 f16;
typedef f16 f16x8 __attribute__((ext_vector_type(8)));
typedef f16 f16x4 __attribute__((ext_vector_type(4)));
typedef float f32x4 __attribute__((ext_vector_type(4)));

#define DDIM    256
#define KCODES  1024
#define NTOK    65536
#define TOKB    64     // tokens per block
#define SMARGIN 0.1f   // score-space margin; == 0.2 in d2 units (d2 gap = 2*score gap)

// ---------------- prep: codebook fp32 -> A-fragment-tiled f16, c2, zero count ----
// Tiled layout: cht[((ct*8 + kt)*64 + L)*8 + j] = f16(cb[ct*16 + (L&15)][kt*32 + (L>>4)*8 + j])
//   (exactly the 16x16x32 MFMA A-operand per-lane layout; verified round 4)
__global__ __launch_bounds__(256) void vq_prep(const float* __restrict__ cb,
                                               f16* __restrict__ cht,
                                               float* __restrict__ c2,
                                               unsigned* __restrict__ count) {
    const int k    = blockIdx.x * 4 + (threadIdx.x >> 6);
    const int lane = threadIdx.x & 63;
    const float4 v = *(const float4*)(cb + (size_t)k * DDIM + 4 * lane);
    f16x4 h; h[0] = (f16)v.x; h[1] = (f16)v.y; h[2] = (f16)v.z; h[3] = (f16)v.w;
    const int ct = k >> 4, m = k & 15;
    const int e  = 4 * lane;            // this thread's 4 consecutive k-elements
    const int kt = e >> 5;
    const int s  = (e & 31) >> 3;       // sub-lane group within k-tile
    const int j0 = e & 7;               // 0 or 4
    const int L  = s * 16 + m;          // fragment lane
    *(f16x4*)(cht + ((size_t)(ct * 8 + kt) * 64 + L) * 8 + j0) = h;
    float ssum = v.x * v.x + v.y * v.y + v.z * v.z + v.w * v.w;
    #pragma unroll
    for (int off = 32; off > 0; off >>= 1) ssum += __shfl_down(ssum, off, 64);
    if (lane == 0) c2[k] = ssum;
    if (blockIdx.x == 0 && threadIdx.x == 0) *count = 0u;
}

// one k-slice: 16 MFMAs consuming AF/BF, then reload AF with slice NS of chunk
// NAP (global) and BF with slice NBS (LDS; chunk-independent -> real prefetch).
#define SLICE(AF, BF, S, NAP, NBS) do {                                             \
    _Pragma("unroll")                                                               \
    for (int ci = 0; ci < 4; ++ci)                                                  \
        _Pragma("unroll")                                                           \
        for (int ti = 0; ti < 4; ++ti)                                              \
            acc[ci][ti] = __builtin_amdgcn_mfma_f32_16x16x32_f16(                   \
                AF[ci], BF[ti], acc[ci][ti], 0, 0, 0);                              \
    _Pragma("unroll")                                                               \
    for (int ci = 0; ci < 4; ++ci)                                                  \
        AF[ci] = *(const f16x8*)((NAP) + ci * 4096 + (NBS) * 512);                  \
    _Pragma("unroll")                                                               \
    for (int ti = 0; ti < 4; ++ti)                                                  \
        BF[ti] = *(const f16x8*)(bls + ((ti * 8 + (NBS)) * 64 + lane) * 8);         \
} while (0)

// ---------------- main: LDS tokens + L2-streamed codes + packed argmax + gather ---
__global__ __launch_bounds__(256, 3) void vq_main(const float* __restrict__ xg,
                                                  const f16* __restrict__ cht,
                                                  const float* __restrict__ c2,
                                                  const float* __restrict__ cb,
                                                  float* __restrict__ out,
                                                  unsigned* __restrict__ count,
                                                  unsigned* __restrict__ list) {
    __shared__ f16   bls[TOKB * DDIM];         // 64 tok x 256 k, B-fragment-tiled: 32 KB
    __shared__ float c2s[KCODES];              // 4 KB
    __shared__ float wmv[4][TOKB];             // per-wave best (packed) score
    __shared__ float wms[4][TOKB];             // per-wave second (packed) score
    __shared__ int   wmi[4][TOKB];
    __shared__ int   idx_s[TOKB];

    const int t    = threadIdx.x;
    const int wave = t >> 6, lane = t & 63;    // wave = code-quarter within chunk
    const int q    = lane >> 4;                // operand quad
    const int m16  = lane & 15;
    const int tok0 = blockIdx.x * TOKB;

    // ---- stage this block's 64 tokens into LDS as B-fragments (once) ----
    // thread t covers row rr = t>>2, elements e = (t&3)*64 + p*4 over 16 passes.
    // bank spread ~8-way on writes (m = rr&15 varies across lanes).
    {
        const int rr = t >> 2;                 // 0..63 block-local token
        const int ti_ = rr >> 4, m = rr & 15;
        const float* xrow = xg + (size_t)(tok0 + rr) * DDIM;
        #pragma unroll
        for (int p = 0; p < 16; ++p) {
            const int e  = (t & 3) * 64 + p * 4;
            const float4 v = *(const float4*)(xrow + e);
            f16x4 h; h[0] = (f16)v.x; h[1] = (f16)v.y; h[2] = (f16)v.z; h[3] = (f16)v.w;
            const int kt = e >> 5;
            const int s  = (e & 31) >> 3;
            const int j0 = e & 7;
            const int L  = s * 16 + m;
            *(f16x4*)(bls + ((ti_ * 8 + kt) * 64 + L) * 8 + j0) = h;
        }
    }
    *(float4*)&c2s[t * 4] = *(const float4*)(c2 + t * 4);
    __syncthreads();                           // bls + c2s visible; only pre-loop barrier

    const f16* aw = cht + wave * 16384 + lane * 8;   // wave's code-quarter A base

    // ---- prime af/bf double-buffers with slices 0,1 ----
    f16x8 afA[4], afB[4], bfA[4], bfB[4];
    #pragma unroll
    for (int ci = 0; ci < 4; ++ci) afA[ci] = *(const f16x8*)(aw + ci * 4096 + 0 * 512);
    #pragma unroll
    for (int ci = 0; ci < 4; ++ci) afB[ci] = *(const f16x8*)(aw + ci * 4096 + 1 * 512);
    #pragma unroll
    for (int ti = 0; ti < 4; ++ti) bfA[ti] = *(const f16x8*)(bls + ((ti * 8 + 0) * 64 + lane) * 8);
    #pragma unroll
    for (int ti = 0; ti < 4; ++ti) bfB[ti] = *(const f16x8*)(bls + ((ti * 8 + 1) * 64 + lane) * 8);

    // running top-2 per ti, PACKED: value bits with (127-j) in mantissa LSBs (r7)
    float rb1[4], rb2[4];
    #pragma unroll
    for (int ti = 0; ti < 4; ++ti) { rb1[ti] = -FLT_MAX; rb2[ti] = -FLT_MAX; }

    #pragma unroll 1
    for (int nc = 0; nc < 4; ++nc) {           // 4 chunks of 256 codes (64/wave)
        f32x4 acc[4][4];                       // [ci][ti], init = -0.5*c2 (score space)
        #pragma unroll
        for (int ci = 0; ci < 4; ++ci) {
            f32x4 cv = *(const f32x4*)&c2s[nc * 256 + wave * 64 + ci * 16 + q * 4];
            cv = cv * -0.5f;
            #pragma unroll
            for (int ti = 0; ti < 4; ++ti) acc[ci][ti] = cv;
        }

        const f16* an = aw + nc * 65536;
        const f16* ax = aw + ((nc + 1) & 3) * 65536;   // wrap: harmless extra loads

        __builtin_amdgcn_s_setprio(1);
        SLICE(afA, bfA, 0, an, 2);             // consume slice s, reload with s+2
        SLICE(afB, bfB, 1, an, 3);
        SLICE(afA, bfA, 2, an, 4);
        SLICE(afB, bfB, 3, an, 5);
        SLICE(afA, bfA, 4, an, 6);
        SLICE(afB, bfB, 5, an, 7);
        SLICE(afA, bfA, 6, ax, 0);             // prefetch next chunk's slices 0,1
        SLICE(afB, bfB, 7, ax, 1);             // (bf wrap = correct data: chunk-indep)
        __builtin_amdgcn_s_setprio(0);

        // ---- per-lane packed top-2 scan (r7-verified), j = nc*16+ci*4+r < 64 ----
        #pragma unroll
        for (int ti = 0; ti < 4; ++ti) {
            #pragma unroll
            for (int ci = 0; ci < 4; ++ci) {
                #pragma unroll
                for (int r = 0; r < 4; ++r) {
                    const unsigned pv = (__float_as_uint(acc[ci][ti][r]) & ~127u)
                                        | (unsigned)(127 - (nc * 16 + ci * 4 + r));
                    const float pf = __uint_as_float(pv);
                    rb2[ti] = fmaxf(rb2[ti], fminf(rb1[ti], pf));  // old rb1
                    rb1[ti] = fmaxf(rb1[ti], pf);
                }
            }
        }
    }

    // ---- decode per-lane index (own q/wave), ONE quad merge, publish ----
    #pragma unroll
    for (int ti = 0; ti < 4; ++ti) {
        const int jj = 127 - (int)(__float_as_uint(rb1[ti]) & 127u);
        int   i1 = (jj >> 4) * 256 + wave * 64 + ((jj >> 2) & 3) * 16 + q * 4 + (jj & 3);
        float b1 = rb1[ti], b2 = rb2[ti];
        #pragma unroll
        for (int sft = 0; sft < 2; ++sft) {    // merge quads (l^16, l^32)
            const int off = 16 << sft;
            const float ob1 = __shfl_xor(b1, off, 64);
            const float ob2 = __shfl_xor(b2, off, 64);
            const int   oi1 = __shfl_xor(i1, off, 64);
            const bool better = (ob1 > b1) || (ob1 == b1 && oi1 < i1);
            b2 = fmaxf(fmaxf(b2, ob2), fminf(b1, ob1));
            b1 = better ? ob1 : b1;
            i1 = better ? oi1 : i1;
        }
        if (lane < 16) {
            const int tl = ti * 16 + m16;
            wmv[wave][tl] = b1; wmi[wave][tl] = i1; wms[wave][tl] = b2;
        }
    }
    __syncthreads();

    // ---- merge 4 waves' top-2 (ascending wave, explicit-index tiebreak), flag ----
    if (t < TOKB) {
        float c1 = wmv[0][t], cs = wms[0][t];
        int   ci_ = wmi[0][t];
        #pragma unroll
        for (int w = 1; w < 4; ++w) {
            const float b1 = wmv[w][t], b2 = wms[w][t];
            const int   bi = wmi[w][t];
            const bool bb = (b1 > c1) || (b1 == c1 && bi < ci_);
            cs = fmaxf(fmaxf(cs, b2), fminf(c1, b1));
            if (bb) { c1 = b1; ci_ = bi; }
        }
        idx_s[t] = ci_;
        if (c1 - cs < SMARGIN) {               // d2 gap = 2*(c1-cs) < 0.2
            const unsigned p = atomicAdd(count, 1u);
            list[p] = tok0 + t;
        }
    }
    __syncthreads();

    // gather epilogue: out[tok] = cb[argmin], coalesced float4
    #pragma unroll
    for (int i = 0; i < 16; ++i) {
        const int f   = i * 256 + t;           // 4096 float4 = 64 tok x 64
        const int tok = f >> 6, d4 = f & 63;
        const int code = idx_s[tok];
        const float4 v = *(const float4*)(cb + (size_t)code * DDIM + 4 * d4);
        *(float4*)(out + (size_t)(tok0 + tok) * DDIM + 4 * d4) = v;
    }
}

// ---------------- rescue: exact fp32 argmin for margin-flagged tokens ----------------
// (verified round 5: 8 tokens/iter, no spill, grid-stride 1024)
__global__ __launch_bounds__(256) void vq_rescue(const float* __restrict__ xg,
                                                 const float* __restrict__ cb,
                                                 const float* __restrict__ c2,
                                                 const unsigned* __restrict__ count,
                                                 const unsigned* __restrict__ list,
                                                 float* __restrict__ out) {
    __shared__ float xls[8][DDIM];             // 8 KB
    __shared__ float rv[4][8];
    __shared__ int   ri[4][8];
    __shared__ int   bidx[8];

    const int t = threadIdx.x;
    const int wave = t >> 6, lane = t & 63;
    const unsigned n = *count;

    for (unsigned base = blockIdx.x * 8; base < n; base += gridDim.x * 8) {
        const int nb = (int)min(8u, n - base);
        __syncthreads();                        // protect xls/rv/bidx reuse
        #pragma unroll
        for (int i = 0; i < 2; ++i) {
            const int f = t + 256 * i;          // 512 float4 slots
            const int row = f >> 6, d4 = f & 63;
            if (row < nb)
                *(float4*)&xls[row][4 * d4] =
                    *(const float4*)(xg + (size_t)list[base + row] * DDIM + 4 * d4);
        }
        __syncthreads();

        float acc[4][8];
        #pragma unroll
        for (int j = 0; j < 4; ++j)
            #pragma unroll
            for (int tk = 0; tk < 8; ++tk) acc[j][tk] = 0.0f;

        for (int d4 = 0; d4 < 64; ++d4) {
            float4 cv[4];
            #pragma unroll
            for (int j = 0; j < 4; ++j)
                cv[j] = *(const float4*)(cb + (size_t)(4 * t + j) * DDIM + 4 * d4);
            #pragma unroll
            for (int tk = 0; tk < 8; ++tk) {
                const float4 xv = *(const float4*)&xls[tk][4 * d4];
                #pragma unroll
                for (int j = 0; j < 4; ++j) {
                    float a = acc[j][tk];       // sequential .x->.w: verified order
                    a = fmaf(cv[j].x, xv.x, a);
                    a = fmaf(cv[j].y, xv.y, a);
                    a = fmaf(cv[j].z, xv.z, a);
                    a = fmaf(cv[j].w, xv.w, a);
                    acc[j][tk] = a;
                }
            }
        }

        // per-token argmin: thread's 4 codes -> wave butterfly -> cross-wave merge
        #pragma unroll
        for (int tk = 0; tk < 8; ++tk) {
            if (tk < nb) {
                float b1 = FLT_MAX; int i1 = 0;
                #pragma unroll
                for (int j = 0; j < 4; ++j) {   // codes 4t..4t+3 ascending
                    const float d = fmaf(-2.0f, acc[j][tk], c2[4 * t + j]);
                    if (d < b1) { b1 = d; i1 = 4 * t + j; }
                }
                #pragma unroll
                for (int off = 32; off > 0; off >>= 1) {
                    const float ov = __shfl_xor(b1, off, 64);
                    const int   oi = __shfl_xor(i1, off, 64);
                    if (ov < b1 || (ov == b1 && oi < i1)) { b1 = ov; i1 = oi; }
                }
                if (lane == 0) { rv[wave][tk] = b1; ri[wave][tk] = i1; }
            }
        }
        __syncthreads();
        if (t < 8 && t < nb) {                  // ascending wave order: same tiebreak
            float bv = rv[0][t]; int bi = ri[0][t];
            #pragma unroll
            for (int w = 1; w < 4; ++w)
                if (rv[w][t] < bv || (rv[w][t] == bv && ri[w][t] < bi)) {
                    bv = rv[w][t]; bi = ri[w][t];
                }
            bidx[t] = bi;
        }
        __syncthreads();

        #pragma unroll
        for (int i = 0; i < 2; ++i) {
            const int f = t + 256 * i;
            const int row = f >> 6, d4 = f & 63;
            if (row < nb) {
                const int code = bidx[row];
                const float4 v = *(const float4*)(cb + (size_t)code * DDIM + 4 * d4);
                *(float4*)(out + (size_t)list[base + row] * DDIM + 4 * d4) = v;
            }
        }
    }
}

extern "C" void kernel_launch(void* const* d_in, const int* in_sizes, int n_in,
                              void* d_out, int out_size, void* d_ws, size_t ws_size,
                              hipStream_t stream) {
    const float* x  = (const float*)d_in[0];   // [B,T,D] fp32
    const float* cb = (const float*)d_in[1];   // [K,D]   fp32
    float* out = (float*)d_out;

    char* ws = (char*)d_ws;
    f16*      cht   = (f16*)ws;                              // 524288 B (tiled)
    float*    c2    = (float*)(ws + 524288);                 // 4096 B
    unsigned* count = (unsigned*)(ws + 528448);              // 4 B (padded)
    unsigned* list  = (unsigned*)(ws + 528512);              // 262144 B

    hipLaunchKernelGGL(vq_prep,   dim3(KCODES / 4), dim3(256), 0, stream, cb, cht, c2, count);
    hipLaunchKernelGGL(vq_main,   dim3(NTOK / TOKB), dim3(256), 0, stream,
                       x, cht, c2, cb, out, count, list);
    hipLaunchKernelGGL(vq_rescue, dim3(1024),       dim3(256), 0, stream,
                       x, cb, c2, count, list, out);
}

// Round 9
// 218.233 us; speedup vs baseline: 1.2942x; 1.2942x over previous
//
#include <hip/hip_runtime.h>
#include <float.h>

// VectorQuantizer: B=16,T=4096,D=256,K=1024 fp32.
// Round 11: tokens-in-LDS WITHOUT the register squeeze.
//   r8 failed exactly as pre-committed: launch_bounds(256,3) -> VGPR 84 vs
//   ~195 demand -> 86MB scratch -> L2 eviction (FETCH 41->194MB). r6 (best,
//   80.6us) itself spilled ~15 regs (WRITE 71.7 vs 65.6MB) with only depth-2
//   af prefetch. Fix: 128-tok blocks, bounds(256,2), bfrag -> LDS (64KB,
//   write-once read-only, zero in-loop barriers; r8-verified mapping),
//   af QUAD-buffer (depth 4 = 8%4==0 phase-stable; ~600cy cover >> L2),
//   bf LDS double-buffer (contiguous conflict-free ds_read_b128),
//   r7-verified packed-index top-2 epilogue. Demand ~190 < 256: no spill.
//   prep = r4 verified (tiled cht); rescue = r5 verified.
//   Score space: score = x.c - 0.5*c2  (argmin d2 == argmax score).

typedef _Float16 f16;
typedef f16 f16x8 __attribute__((ext_vector_type(8)));
typedef f16 f16x4 __attribute__((ext_vector_type(4)));
typedef float f32x4 __attribute__((ext_vector_type(4)));

#define DDIM    256
#define KCODES  1024
#define NTOK    65536
#define TOKB    128    // tokens per block
#define SMARGIN 0.1f   // score-space margin; == 0.2 in d2 units (d2 gap = 2*score gap)

// ---------------- prep: codebook fp32 -> A-fragment-tiled f16, c2, zero count ----
// Tiled layout: cht[((ct*8 + kt)*64 + L)*8 + j] = f16(cb[ct*16 + (L&15)][kt*32 + (L>>4)*8 + j])
//   (exactly the 16x16x32 MFMA A-operand per-lane layout; verified round 4)
__global__ __launch_bounds__(256) void vq_prep(const float* __restrict__ cb,
                                               f16* __restrict__ cht,
                                               float* __restrict__ c2,
                                               unsigned* __restrict__ count) {
    const int k    = blockIdx.x * 4 + (threadIdx.x >> 6);
    const int lane = threadIdx.x & 63;
    const float4 v = *(const float4*)(cb + (size_t)k * DDIM + 4 * lane);
    f16x4 h; h[0] = (f16)v.x; h[1] = (f16)v.y; h[2] = (f16)v.z; h[3] = (f16)v.w;
    const int ct = k >> 4, m = k & 15;
    const int e  = 4 * lane;            // this thread's 4 consecutive k-elements
    const int kt = e >> 5;
    const int s  = (e & 31) >> 3;       // sub-lane group within k-tile
    const int j0 = e & 7;               // 0 or 4
    const int L  = s * 16 + m;          // fragment lane
    *(f16x4*)(cht + ((size_t)(ct * 8 + kt) * 64 + L) * 8 + j0) = h;
    float ssum = v.x * v.x + v.y * v.y + v.z * v.z + v.w * v.w;
    #pragma unroll
    for (int off = 32; off > 0; off >>= 1) ssum += __shfl_down(ssum, off, 64);
    if (lane == 0) c2[k] = ssum;
    if (blockIdx.x == 0 && threadIdx.x == 0) *count = 0u;
}

// one k-slice: 16 MFMAs consuming AF/BF, then AF <- slice NSA of chunk AP
// (global, depth-4), BF <- slice NSB (LDS, chunk-independent, depth-2).
#define SLICE(AF, BF, S, AP, NSA, NSB) do {                                         \
    _Pragma("unroll")                                                               \
    for (int ci = 0; ci < 4; ++ci)                                                  \
        _Pragma("unroll")                                                           \
        for (int ti = 0; ti < 4; ++ti)                                              \
            acc[ci][ti] = __builtin_amdgcn_mfma_f32_16x16x32_f16(                   \
                AF[ci], BF[ti], acc[ci][ti], 0, 0, 0);                              \
    _Pragma("unroll")                                                               \
    for (int ci = 0; ci < 4; ++ci)                                                  \
        AF[ci] = *(const f16x8*)((AP) + ci * 4096 + (NSA) * 512);                   \
    _Pragma("unroll")                                                               \
    for (int ti = 0; ti < 4; ++ti)                                                  \
        BF[ti] = *(const f16x8*)(&bls[tnoff + ((ti * 8 + (NSB)) * 64 + lane) * 8]); \
} while (0)

// ---------------- main: LDS tokens + depth-4 L2 code stream + packed argmax -------
__global__ __launch_bounds__(256, 2) void vq_main(const float* __restrict__ xg,
                                                  const f16* __restrict__ cht,
                                                  const float* __restrict__ c2,
                                                  const float* __restrict__ cb,
                                                  float* __restrict__ out,
                                                  unsigned* __restrict__ count,
                                                  unsigned* __restrict__ list) {
    __shared__ f16   bls[TOKB * DDIM];         // 128 tok x 256 k, B-fragment order: 64 KB
    __shared__ float c2s[KCODES];              // 4 KB
    __shared__ float wmv[2][TOKB];             // per code-half best (packed) score
    __shared__ float wms[2][TOKB];             // per code-half second (packed) score
    __shared__ int   wmi[2][TOKB];
    __shared__ int   idx_s[TOKB];

    const int t    = threadIdx.x;
    const int wave = t >> 6, lane = t & 63;
    const int wm   = wave >> 1;                // code-half (M)
    const int tn   = wave & 1;                 // token-half (N): 64 tokens
    const int q    = lane >> 4;                // operand quad
    const int m16  = lane & 15;
    const int tok0 = blockIdx.x * TOKB;
    const int tnoff = tn * 16384;              // tn's 4 B-tiles in bls (f16 units)

    // ---- stage 128 tokens into LDS as B-fragments (coalesced reads, once) ----
    // pass i: wave w reads row (i*4 + w), 1KB contiguous per wave per pass.
    #pragma unroll
    for (int i = 0; i < 32; ++i) {
        const int g  = i * 1024 + t * 4;       // block-local float index (coalesced)
        const int rr = g >> 8;                 // token row 0..127
        const int e  = g & 255;
        const float4 v = *(const float4*)(xg + (size_t)(tok0 + rr) * DDIM + e);
        f16x4 h; h[0] = (f16)v.x; h[1] = (f16)v.y; h[2] = (f16)v.z; h[3] = (f16)v.w;
        const int kt  = e >> 5;
        const int s   = (e & 31) >> 3;
        const int j0  = e & 7;                 // 0 or 4
        const int ti_ = rr >> 4, m = rr & 15;
        *(f16x4*)(&bls[((ti_ * 8 + kt) * 64 + s * 16 + m) * 8 + j0]) = h;
    }
    *(float4*)&c2s[t * 4] = *(const float4*)(c2 + t * 4);
    __syncthreads();                           // bls + c2s visible; only pre-loop barrier

    const f16* aw = cht + wm * 16384 + lane * 8;   // wave's code-half A base (r6 layout)

    // ---- prime af quad-buffer (chunk-0 slices 0..3) and bf double-buffer ----
    f16x8 afA[4], afB[4], afC[4], afD[4], bfA[4], bfB[4];
    #pragma unroll
    for (int ci = 0; ci < 4; ++ci) {
        afA[ci] = *(const f16x8*)(aw + ci * 4096 + 0 * 512);
        afB[ci] = *(const f16x8*)(aw + ci * 4096 + 1 * 512);
        afC[ci] = *(const f16x8*)(aw + ci * 4096 + 2 * 512);
        afD[ci] = *(const f16x8*)(aw + ci * 4096 + 3 * 512);
    }
    #pragma unroll
    for (int ti = 0; ti < 4; ++ti) {
        bfA[ti] = *(const f16x8*)(&bls[tnoff + ((ti * 8 + 0) * 64 + lane) * 8]);
        bfB[ti] = *(const f16x8*)(&bls[tnoff + ((ti * 8 + 1) * 64 + lane) * 8]);
    }

    // running top-2 per ti, PACKED: value bits with (127-j) in mantissa LSBs (r7)
    float rb1[4], rb2[4];
    #pragma unroll
    for (int ti = 0; ti < 4; ++ti) { rb1[ti] = -FLT_MAX; rb2[ti] = -FLT_MAX; }

    #pragma unroll 1
    for (int nc = 0; nc < 8; ++nc) {           // 8 chunks of 128 codes
        f32x4 acc[4][4];                       // [ci][ti], init = -0.5*c2 (score space)
        #pragma unroll
        for (int ci = 0; ci < 4; ++ci) {
            f32x4 cv = *(const f32x4*)&c2s[nc * 128 + wm * 64 + ci * 16 + q * 4];
            cv = cv * -0.5f;
            #pragma unroll
            for (int ti = 0; ti < 4; ++ti) acc[ci][ti] = cv;
        }

        const f16* an = aw + nc * 32768;
        const f16* ax = aw + ((nc + 1) & 7) * 32768;   // wrap: harmless extra loads

        __builtin_amdgcn_s_setprio(1);
        SLICE(afA, bfA, 0, an, 4, 2);          // use slice s; af <- s+4, bf <- (s+2)&7
        SLICE(afB, bfB, 1, an, 5, 3);
        SLICE(afC, bfA, 2, an, 6, 4);
        SLICE(afD, bfB, 3, an, 7, 5);
        SLICE(afA, bfA, 4, ax, 0, 6);          // af prefetch rolls into next chunk
        SLICE(afB, bfB, 5, ax, 1, 7);
        SLICE(afC, bfA, 6, ax, 2, 0);          // bf wrap = same data (chunk-indep)
        SLICE(afD, bfB, 7, ax, 3, 1);
        __builtin_amdgcn_s_setprio(0);

        // ---- per-lane packed top-2 scan (r7-verified), j = nc*16+ci*4+r <= 127 ----
        #pragma unroll
        for (int ti = 0; ti < 4; ++ti) {
            #pragma unroll
            for (int ci = 0; ci < 4; ++ci) {
                #pragma unroll
                for (int r = 0; r < 4; ++r) {
                    const unsigned pv = (__float_as_uint(acc[ci][ti][r]) & ~127u)
                                        | (unsigned)(127 - (nc * 16 + ci * 4 + r));
                    const float pf = __uint_as_float(pv);
                    rb2[ti] = fmaxf(rb2[ti], fminf(rb1[ti], pf));  // old rb1
                    rb1[ti] = fmaxf(rb1[ti], pf);
                }
            }
        }
    }

    // ---- decode per-lane index (own q/wm), ONE quad merge, publish (r7) ----
    #pragma unroll
    for (int ti = 0; ti < 4; ++ti) {
        const int jj = 127 - (int)(__float_as_uint(rb1[ti]) & 127u);
        int   i1 = (jj >> 4) * 128 + wm * 64 + ((jj >> 2) & 3) * 16 + q * 4 + (jj & 3);
        float b1 = rb1[ti], b2 = rb2[ti];
        #pragma unroll
        for (int sft = 0; sft < 2; ++sft) {    // merge quads (l^16, l^32)
            const int off = 16 << sft;
            const float ob1 = __shfl_xor(b1, off, 64);
            const float ob2 = __shfl_xor(b2, off, 64);
            const int   oi1 = __shfl_xor(i1, off, 64);
            const bool better = (ob1 > b1) || (ob1 == b1 && oi1 < i1);
            b2 = fmaxf(fmaxf(b2, ob2), fminf(b1, ob1));
            b1 = better ? ob1 : b1;
            i1 = better ? oi1 : i1;
        }
        if (lane < 16) {
            const int tl = tn * 64 + ti * 16 + m16;
            wmv[wm][tl] = b1; wmi[wm][tl] = i1; wms[wm][tl] = b2;
        }
    }
    __syncthreads();

    // ---- merge code-halves, flag, gather (verified r4/r6) ----
    if (t < TOKB) {
        const float a1 = wmv[0][t], a2 = wms[0][t];
        const int   ai = wmi[0][t];
        const float b1_ = wmv[1][t], b2_ = wms[1][t];
        const int   bi_ = wmi[1][t];
        const bool bb = (b1_ > a1) || (b1_ == a1 && bi_ < ai);
        const float c1 = bb ? b1_ : a1;
        const int   ci_ = bb ? bi_ : ai;
        const float cs = fmaxf(fmaxf(a2, b2_), fminf(a1, b1_));
        idx_s[t] = ci_;
        if (c1 - cs < SMARGIN) {               // d2 gap = 2*(c1-cs) < 0.2
            const unsigned p = atomicAdd(count, 1u);
            list[p] = tok0 + t;
        }
    }
    __syncthreads();

    // gather epilogue: out[tok] = cb[argmin], coalesced float4
    #pragma unroll
    for (int i = 0; i < 32; ++i) {
        const int f   = i * 256 + t;           // 8192 float4 = 128 tok x 64
        const int tok = f >> 6, d4 = f & 63;
        const int code = idx_s[tok];
        const float4 v = *(const float4*)(cb + (size_t)code * DDIM + 4 * d4);
        *(float4*)(out + (size_t)(tok0 + tok) * DDIM + 4 * d4) = v;
    }
}

// ---------------- rescue: exact fp32 argmin for margin-flagged tokens ----------------
// (verified round 5: 8 tokens/iter, no spill, grid-stride 1024)
__global__ __launch_bounds__(256) void vq_rescue(const float* __restrict__ xg,
                                                 const float* __restrict__ cb,
                                                 const float* __restrict__ c2,
                                                 const unsigned* __restrict__ count,
                                                 const unsigned* __restrict__ list,
                                                 float* __restrict__ out) {
    __shared__ float xls[8][DDIM];             // 8 KB
    __shared__ float rv[4][8];
    __shared__ int   ri[4][8];
    __shared__ int   bidx[8];

    const int t = threadIdx.x;
    const int wave = t >> 6, lane = t & 63;
    const unsigned n = *count;

    for (unsigned base = blockIdx.x * 8; base < n; base += gridDim.x * 8) {
        const int nb = (int)min(8u, n - base);
        __syncthreads();                        // protect xls/rv/bidx reuse
        #pragma unroll
        for (int i = 0; i < 2; ++i) {
            const int f = t + 256 * i;          // 512 float4 slots
            const int row = f >> 6, d4 = f & 63;
            if (row < nb)
                *(float4*)&xls[row][4 * d4] =
                    *(const float4*)(xg + (size_t)list[base + row] * DDIM + 4 * d4);
        }
        __syncthreads();

        float acc[4][8];
        #pragma unroll
        for (int j = 0; j < 4; ++j)
            #pragma unroll
            for (int tk = 0; tk < 8; ++tk) acc[j][tk] = 0.0f;

        for (int d4 = 0; d4 < 64; ++d4) {
            float4 cv[4];
            #pragma unroll
            for (int j = 0; j < 4; ++j)
                cv[j] = *(const float4*)(cb + (size_t)(4 * t + j) * DDIM + 4 * d4);
            #pragma unroll
            for (int tk = 0; tk < 8; ++tk) {
                const float4 xv = *(const float4*)&xls[tk][4 * d4];
                #pragma unroll
                for (int j = 0; j < 4; ++j) {
                    float a = acc[j][tk];       // sequential .x->.w: verified order
                    a = fmaf(cv[j].x, xv.x, a);
                    a = fmaf(cv[j].y, xv.y, a);
                    a = fmaf(cv[j].z, xv.z, a);
                    a = fmaf(cv[j].w, xv.w, a);
                    acc[j][tk] = a;
                }
            }
        }

        // per-token argmin: thread's 4 codes -> wave butterfly -> cross-wave merge
        #pragma unroll
        for (int tk = 0; tk < 8; ++tk) {
            if (tk < nb) {
                float b1 = FLT_MAX; int i1 = 0;
                #pragma unroll
                for (int j = 0; j < 4; ++j) {   // codes 4t..4t+3 ascending
                    const float d = fmaf(-2.0f, acc[j][tk], c2[4 * t + j]);
                    if (d < b1) { b1 = d; i1 = 4 * t + j; }
                }
                #pragma unroll
                for (int off = 32; off > 0; off >>= 1) {
                    const float ov = __shfl_xor(b1, off, 64);
                    const int   oi = __shfl_xor(i1, off, 64);
                    if (ov < b1 || (ov == b1 && oi < i1)) { b1 = ov; i1 = oi; }
                }
                if (lane == 0) { rv[wave][tk] = b1; ri[wave][tk] = i1; }
            }
        }
        __syncthreads();
        if (t < 8 && t < nb) {                  // ascending wave order: same tiebreak
            float bv = rv[0][t]; int bi = ri[0][t];
            #pragma unroll
            for (int w = 1; w < 4; ++w)
                if (rv[w][t] < bv || (rv[w][t] == bv && ri[w][t] < bi)) {
                    bv = rv[w][t]; bi = ri[w][t];
                }
            bidx[t] = bi;
        }
        __syncthreads();

        #pragma unroll
        for (int i = 0; i < 2; ++i) {
            const int f = t + 256 * i;
            const int row = f >> 6, d4 = f & 63;
            if (row < nb) {
                const int code = bidx[row];
                const float4 v = *(const float4*)(cb + (size_t)code * DDIM + 4 * d4);
                *(float4*)(out + (size_t)list[base + row] * DDIM + 4 * d4) = v;
            }
        }
    }
}

extern "C" void kernel_launch(void* const* d_in, const int* in_sizes, int n_in,
                              void* d_out, int out_size, void* d_ws, size_t ws_size,
                              hipStream_t stream) {
    const float* x  = (const float*)d_in[0];   // [B,T,D] fp32
    const float* cb = (const float*)d_in[1];   // [K,D]   fp32
    float* out = (float*)d_out;

    char* ws = (char*)d_ws;
    f16*      cht   = (f16*)ws;                              // 524288 B (tiled)
    float*    c2    = (float*)(ws + 524288);                 // 4096 B
    unsigned* count = (unsigned*)(ws + 528448);              // 4 B (padded)
    unsigned* list  = (unsigned*)(ws + 528512);              // 262144 B

    hipLaunchKernelGGL(vq_prep,   dim3(KCODES / 4), dim3(256), 0, stream, cb, cht, c2, count);
    hipLaunchKernelGGL(vq_main,   dim3(NTOK / TOKB), dim3(256), 0, stream,
                       x, cht, c2, cb, out, count, list);
    hipLaunchKernelGGL(vq_rescue, dim3(1024),       dim3(256), 0, stream,
                       x, cb, c2, count, list, out);
}